// Round 9
// baseline (9976.825 us; speedup 1.0000x reference)
//
#include <hip/hip_runtime.h>

// ---------- types ----------
typedef float  f32x4  __attribute__((ext_vector_type(4)));
typedef short  short8 __attribute__((ext_vector_type(8)));
typedef __bf16 bf16x8 __attribute__((ext_vector_type(8)));

#define B_SZ 2048
#define T_SZ 120
#define H_SZ 256
#define G3   768      // 3H
#define A_SZ 40

#define MFMA_BF16 __builtin_amdgcn_mfma_f32_16x16x32_bf16

union U8 { short8 s; bf16x8 b; };
__device__ __forceinline__ bf16x8 as_bf(short8 s){ U8 u; u.s = s; return u.b; }

__device__ __forceinline__ unsigned short f2bf(float x){
  unsigned u = __float_as_uint(x);
  return (unsigned short)((u + 0x7FFFu + ((u >> 16) & 1u)) >> 16);
}
__device__ __forceinline__ float bf2f(unsigned short h){
  return __uint_as_float(((unsigned)h) << 16);
}
__device__ __forceinline__ void cvt_hilo(float x, short& hi, short& lo){
  unsigned short h = f2bf(x);
  hi = (short)h;
  lo = (short)f2bf(x - bf2f(h));
}
__device__ __forceinline__ float sigm(float x){ return 1.0f / (1.0f + __expf(-x)); }
__device__ __forceinline__ float tanh_(float x){
  float a = fabsf(x);
  float t = 1.0f - 2.0f / (__expf(2.0f * a) + 1.0f);
  return copysignf(t, x);
}

// ---------- zero-init scratch state ----------
__global__ void zinit(float* __restrict__ p, size_t n){
  size_t i = (size_t)blockIdx.x * 256 + threadIdx.x;
  size_t stride = (size_t)gridDim.x * 256;
  for (; i < n; i += stride) p[i] = 0.0f;
}

// ---------- weight packing: W[G3 x K] fp32 -> MFMA-B bricks, bf16 hi ----------
__global__ void packw_h(const float* __restrict__ W, int K, short* __restrict__ hi){
  int KT = K >> 5;
  int nt = blockIdx.x / KT;
  int kt = blockIdx.x % KT;
  int lane = threadIdx.x;            // 64
  const float* src = W + (size_t)(nt * 16 + (lane & 15)) * K + kt * 32 + (lane >> 4) * 8;
  size_t o = (((size_t)nt * KT + kt) * 64 + lane) * 8;
#pragma unroll
  for (int i = 0; i < 8; i++) hi[o + i] = (short)f2bf(src[i]);
}

// ---------- input-projection GEMM (inter only): 2-pass (A split hi/lo, B hi) ----------
__global__ __launch_bounds__(512, 1) void gemm2p(
    const float* __restrict__ A, int K, int rowT, int t0, int tcnt,
    const short* __restrict__ Bhi,
    const float* __restrict__ b1, const float* __restrict__ b2,
    float* __restrict__ C)
{
  int tid = threadIdx.x;
  int w = tid >> 6, lane = tid & 63;
  int mg = w & 1, ng = w >> 1;         // ng 0..3
  int m0 = blockIdx.x * 64 + mg * 32;
  int nb = ng * 12;
  int KT = K >> 5;
  const f32x4 zero = {0.f, 0.f, 0.f, 0.f};
  f32x4 acc[2][12];
#pragma unroll
  for (int f = 0; f < 2; f++)
#pragma unroll
    for (int q = 0; q < 12; q++) acc[f][q] = zero;

  int rr = lane & 15, ks = lane >> 4;
  const float* Ap[2];
#pragma unroll
  for (int f = 0; f < 2; f++){
    int r = m0 + f * 16 + rr;
    size_t ar;
    if (rowT){
      int b = r / tcnt;
      int tc = r - b * tcnt;
      ar = (size_t)b * rowT + t0 + tc;
    } else {
      ar = (size_t)r;
    }
    Ap[f] = A + ar * K + ks * 8;
  }

  for (int kt = 0; kt < KT; ++kt){
    bf16x8 ahb[2], alb[2];
#pragma unroll
    for (int f = 0; f < 2; f++){
      f32x4 a0 = *(const f32x4*)(Ap[f] + kt * 32);
      f32x4 a1 = *(const f32x4*)(Ap[f] + kt * 32 + 4);
      short8 ah, al;
#pragma unroll
      for (int i = 0; i < 4; i++){
        short h, l;
        cvt_hilo(a0[i], h, l); ah[i] = h;   al[i] = l;
        cvt_hilo(a1[i], h, l); ah[i+4] = h; al[i+4] = l;
      }
      ahb[f] = as_bf(ah); alb[f] = as_bf(al);
    }
#pragma unroll
    for (int q = 0; q < 12; q++){
      int bo = (((nb + q) * KT + kt) * 64 + lane) * 8;
      bf16x8 bh = as_bf(*(const short8*)(Bhi + bo));
#pragma unroll
      for (int f = 0; f < 2; f++){
        acc[f][q] = MFMA_BF16(ahb[f], bh, acc[f][q], 0, 0, 0);
        acc[f][q] = MFMA_BF16(alb[f], bh, acc[f][q], 0, 0, 0);
      }
    }
  }
  int nc = lane & 15;
  int rb = lane >> 4;
#pragma unroll
  for (int q = 0; q < 12; q++){
    int n = (nb + q) * 16 + nc;
    float bias = b1[n] + (n < 512 ? b2[n] : 0.0f);
#pragma unroll
    for (int f = 0; f < 2; f++)
#pragma unroll
      for (int i = 0; i < 4; i++)
        C[(size_t)(m0 + f * 16 + rb * 4 + i) * G3 + n] = acc[f][q][i] + bias;
  }
}

// ---------- fused leaf GRU: 8 rows/WG (2 blocks/CU), gates in registers ----------
// A-frag rows 8..15 duplicate rows 0..7 (arow&7); only rows<8 store.
template<int D, int KI>
__device__ __forceinline__ void leaf_body(
    const float* __restrict__ x, const short* __restrict__ Wih,
    const short* __restrict__ Whh, const float* __restrict__ bih,
    const float* __restrict__ bhh, float* __restrict__ outp, int ooff,
    float* __restrict__ hs, int b0, int t0, int tcnt,
    short* hhi, short* hlo, short* xhi)
{
  constexpr int XP  = D + 8;          // padded LDS row (shorts)
  constexpr int NST = D;              // staging threads = 8*D/8
  constexpr int CPR = D / 8;
  int tid = threadIdx.x, w = tid >> 6, lane = tid & 63;
  int arow = lane & 15, kgrp = lane >> 4;
  int ar7 = arow & 7;
  int c0 = w * 16 + arow;
  int msk = ar7 << 4;

  float bir[2], biz[2], bin_[2], bhn[2];
#pragma unroll
  for (int j = 0; j < 2; j++){
    int c = c0 + j * 128;
    bir[j] = bih[c] + bhh[c];
    biz[j] = bih[256 + c] + bhh[256 + c];
    bin_[j] = bih[512 + c];
    bhn[j] = bhh[512 + c];
  }

  int srow = tid / CPR, scol = (tid % CPR) * 8;
  bool stg = tid < NST;
  const float* sx = x + ((size_t)(b0 + srow) * T_SZ + t0) * D + scol;
  short* xwh = xhi + srow * XP + scol;

  // h init: fp32 regs + LDS hi/lo (rows 0..7 only)
  float hreg[2][4];
#pragma unroll
  for (int j = 0; j < 2; j++)
#pragma unroll
  for (int i = 0; i < 4; i++){
    int row = kgrp * 4 + i, rowc = row & 7, c = c0 + j * 128;
    float v = hs[(size_t)(b0 + rowc) * H_SZ + c];
    hreg[j][i] = v;
    if (row < 8){
      short h_, l_; cvt_hilo(v, h_, l_);
      int off = rowc * 512 + ((c * 2) ^ (rowc << 4));
      *(short*)((char*)hhi + off) = h_;
      *(short*)((char*)hlo + off) = l_;
    }
  }
  if (stg){
    f32x4 a0 = *(const f32x4*)sx;
    f32x4 a1 = *(const f32x4*)(sx + 4);
    short8 h8;
#pragma unroll
    for (int i = 0; i < 4; i++){ h8[i] = (short)f2bf(a0[i]); h8[4+i] = (short)f2bf(a1[i]); }
    *(short8*)xwh = h8;
  }
  __syncthreads();

  const char* hhp = (const char*)hhi + ar7 * 512;
  const char* hlp = (const char*)hlo + ar7 * 512;
  const char* xhp = (const char*)xhi + (ar7 * XP + kgrp * 8) * 2;

  const f32x4 zero = {0.f, 0.f, 0.f, 0.f};
  for (int t = 0; t < tcnt; t++){
    f32x4 acc[6], accNi[2];
#pragma unroll
    for (int q = 0; q < 6; q++) acc[q] = zero;
    accNi[0] = zero; accNi[1] = zero;

    // ---- ih phase: x-hi from LDS ----
#pragma unroll
    for (int kt = 0; kt < KI; kt++){
      short8 wb[6];
#pragma unroll
      for (int q = 0; q < 6; q++)
        wb[q] = *(const short8*)(Wih + (((w + 8 * q) * KI + kt) * 64 + lane) * 8);
      bf16x8 ah = as_bf(*(const short8*)(xhp + kt * 64));
#pragma unroll
      for (int q = 0; q < 6; q++){
        bf16x8 bw = as_bf(wb[q]);
        if (q < 4) acc[q] = MFMA_BF16(ah, bw, acc[q], 0, 0, 0);
        else       accNi[q-4] = MFMA_BF16(ah, bw, accNi[q-4], 0, 0, 0);
      }
    }
    // ---- hh phase: h hi/lo from LDS ----
#pragma unroll
    for (int kt = 0; kt < 8; kt++){
      short8 wb[6];
#pragma unroll
      for (int q = 0; q < 6; q++)
        wb[q] = *(const short8*)(Whh + (((w + 8 * q) * 8 + kt) * 64 + lane) * 8);
      int kb = (kt * 64 + kgrp * 16) ^ msk;
      bf16x8 ah = as_bf(*(const short8*)(hhp + kb));
      bf16x8 al = as_bf(*(const short8*)(hlp + kb));
#pragma unroll
      for (int q = 0; q < 6; q++){
        bf16x8 bw = as_bf(wb[q]);
        acc[q] = MFMA_BF16(ah, bw, acc[q], 0, 0, 0);
        acc[q] = MFMA_BF16(al, bw, acc[q], 0, 0, 0);
      }
    }
    __syncthreads();   // b1: LDS reads done

    f32x4 a0, a1;
    bool ds = stg && (t + 1 < tcnt);
    if (ds){
      a0 = *(const f32x4*)(sx + (size_t)(t + 1) * D);
      a1 = *(const f32x4*)(sx + (size_t)(t + 1) * D + 4);
    }

    // ---- gates in registers ----
#pragma unroll
    for (int j = 0; j < 2; j++)
#pragma unroll
    for (int i = 0; i < 4; i++){
      float rr = sigm(acc[j][i] + bir[j]);
      float zz = sigm(acc[2 + j][i] + biz[j]);
      float nn = tanh_(accNi[j][i] + bin_[j] + rr * (acc[4 + j][i] + bhn[j]));
      float hv = (1.0f - zz) * nn + zz * hreg[j][i];
      hreg[j][i] = hv;
      int row = kgrp * 4 + i;
      if (row < 8){
        int c = c0 + j * 128;
        outp[((size_t)(b0 + row) * tcnt + t) * 512 + ooff + c] = hv;
        short h_, l_; cvt_hilo(hv, h_, l_);
        int off = row * 512 + ((c * 2) ^ (row << 4));
        *(short*)((char*)hhi + off) = h_;
        *(short*)((char*)hlo + off) = l_;
      }
    }
    if (ds){
      short8 h8;
#pragma unroll
      for (int i = 0; i < 4; i++){ h8[i] = (short)f2bf(a0[i]); h8[4+i] = (short)f2bf(a1[i]); }
      *(short8*)xwh = h8;
    }
    __syncthreads();   // b2
  }

#pragma unroll
  for (int j = 0; j < 2; j++)
#pragma unroll
  for (int i = 0; i < 4; i++){
    int row = kgrp * 4 + i;
    if (row < 8)
      hs[(size_t)(b0 + row) * H_SZ + c0 + j * 128] = hreg[j][i];
  }
}

__global__ __launch_bounds__(512, 4) void gru_leaf(
    const float* __restrict__ x0, const short* __restrict__ Wih0,
    const short* __restrict__ Whh0, const float* __restrict__ bih0,
    const float* __restrict__ bhh0, float* __restrict__ out0, int ooff0,
    float* __restrict__ hs0,
    const float* __restrict__ x1, const short* __restrict__ Wih1,
    const short* __restrict__ Whh1, const float* __restrict__ bih1,
    const float* __restrict__ bhh1, float* __restrict__ out1, int ooff1,
    float* __restrict__ hs1,
    int nwg0, int t0, int tcnt)
{
  __shared__ short hhi[8 * 256];   // 4 KB
  __shared__ short hlo[8 * 256];   // 4 KB
  __shared__ short xhi[8 * 136];   // 2.1 KB (D<=128, pad 8)
  if ((int)blockIdx.x < nwg0)
    leaf_body<128, 4>(x0, Wih0, Whh0, bih0, bhh0, out0, ooff0, hs0,
                      blockIdx.x * 8, t0, tcnt, hhi, hlo, xhi);
  else
    leaf_body<96, 3>(x1, Wih1, Whh1, bih1, bhh1, out1, ooff1, hs1,
                     (blockIdx.x - nwg0) * 8, t0, tcnt, hhi, hlo, xhi);
}

// ---------- inter GRU: 8 rows/WG, 256 WGs (full GPU), gi precomputed ----------
__global__ __launch_bounds__(512, 4) void gru_inter(
    const float* __restrict__ gi,       // [B*tcnt, 768] chunk-local
    const short* __restrict__ Whh, const float* __restrict__ bhh,
    float* __restrict__ outp, float* __restrict__ hs, int tcnt)
{
  __shared__ short hhi[8 * 256];
  __shared__ short hlo[8 * 256];
  int b0 = blockIdx.x * 8;
  int tid = threadIdx.x, w = tid >> 6, lane = tid & 63;
  int arow = lane & 15, kgrp = lane >> 4;
  int ar7 = arow & 7;
  int c0 = w * 16 + arow;
  int msk = ar7 << 4;

  float bhn[2];
  bhn[0] = bhh[512 + c0];
  bhn[1] = bhh[512 + c0 + 128];

  float hreg[2][4];
#pragma unroll
  for (int j = 0; j < 2; j++)
#pragma unroll
  for (int i = 0; i < 4; i++){
    int row = kgrp * 4 + i, rowc = row & 7, c = c0 + j * 128;
    float v = hs[(size_t)(b0 + rowc) * H_SZ + c];
    hreg[j][i] = v;
    if (row < 8){
      short h_, l_; cvt_hilo(v, h_, l_);
      int off = rowc * 512 + ((c * 2) ^ (rowc << 4));
      *(short*)((char*)hhi + off) = h_;
      *(short*)((char*)hlo + off) = l_;
    }
  }
  __syncthreads();

  const char* hhp = (const char*)hhi + ar7 * 512;
  const char* hlp = (const char*)hlo + ar7 * 512;
  const float* gp[4];
#pragma unroll
  for (int i = 0; i < 4; i++)
    gp[i] = gi + (size_t)(b0 + ((kgrp * 4 + i) & 7)) * tcnt * G3;

  const f32x4 zero = {0.f, 0.f, 0.f, 0.f};
  for (int t = 0; t < tcnt; t++){
    // gi loads at step top (hide under MFMA phase)
    float gvr[2][4], gvz[2][4], gvn[2][4];
#pragma unroll
    for (int j = 0; j < 2; j++)
#pragma unroll
    for (int i = 0; i < 4; i++){
      const float* g = gp[i] + (size_t)t * G3 + c0 + j * 128;
      gvr[j][i] = g[0];
      gvz[j][i] = g[256];
      gvn[j][i] = g[512];
    }

    f32x4 acc[6];
#pragma unroll
    for (int q = 0; q < 6; q++) acc[q] = zero;

#pragma unroll
    for (int kt = 0; kt < 8; kt++){
      short8 wb[6];
#pragma unroll
      for (int q = 0; q < 6; q++)
        wb[q] = *(const short8*)(Whh + (((w + 8 * q) * 8 + kt) * 64 + lane) * 8);
      int kb = (kt * 64 + kgrp * 16) ^ msk;
      bf16x8 ah = as_bf(*(const short8*)(hhp + kb));
      bf16x8 al = as_bf(*(const short8*)(hlp + kb));
#pragma unroll
      for (int q = 0; q < 6; q++){
        bf16x8 bw = as_bf(wb[q]);
        acc[q] = MFMA_BF16(ah, bw, acc[q], 0, 0, 0);
        acc[q] = MFMA_BF16(al, bw, acc[q], 0, 0, 0);
      }
    }
    __syncthreads();   // b1

#pragma unroll
    for (int j = 0; j < 2; j++)
#pragma unroll
    for (int i = 0; i < 4; i++){
      float rr = sigm(gvr[j][i] + acc[j][i]);
      float zz = sigm(gvz[j][i] + acc[2 + j][i]);
      float nn = tanh_(gvn[j][i] + rr * (acc[4 + j][i] + bhn[j]));
      float hv = (1.0f - zz) * nn + zz * hreg[j][i];
      hreg[j][i] = hv;
      int row = kgrp * 4 + i;
      if (row < 8){
        int c = c0 + j * 128;
        outp[((size_t)(b0 + row) * tcnt + t) * H_SZ + c] = hv;
        short h_, l_; cvt_hilo(hv, h_, l_);
        int off = row * 512 + ((c * 2) ^ (row << 4));
        *(short*)((char*)hhi + off) = h_;
        *(short*)((char*)hlo + off) = l_;
      }
    }
    __syncthreads();   // b2
  }

#pragma unroll
  for (int j = 0; j < 2; j++)
#pragma unroll
  for (int i = 0; i < 4; i++){
    int row = kgrp * 4 + i;
    if (row < 8)
      hs[(size_t)(b0 + row) * H_SZ + c0 + j * 128] = hreg[j][i];
  }
}

// ---------- attention scores: 2 rows/thread (halved LDS traffic) ----------
__global__ __launch_bounds__(256, 1) void attn_scores(
    const float* __restrict__ outi, const float* __restrict__ Wv,
    const float* __restrict__ bv, const float* __restrict__ wu,
    float* __restrict__ sc, int t0, int tcnt)
{
  __shared__ float swv[A_SZ * H_SZ];
  __shared__ float sbu[A_SZ], sbv[A_SZ];
  int tid = threadIdx.x;
  for (int i = tid; i < A_SZ * H_SZ; i += 256) swv[i] = Wv[i];
  if (tid < A_SZ){ sbu[tid] = wu[tid]; sbv[tid] = bv[tid]; }
  __syncthreads();
  int r0 = blockIdx.x * 512 + tid;     // rows r0 and r0+256 (chunk-local)
  int r1 = r0 + 256;
  const float* x0 = outi + (size_t)r0 * H_SZ;
  const float* x1 = outi + (size_t)r1 * H_SZ;
  float acc0[A_SZ], acc1[A_SZ];
#pragma unroll
  for (int a = 0; a < A_SZ; a++){ acc0[a] = 0.f; acc1[a] = 0.f; }
  for (int h = 0; h < H_SZ; h += 4){
    f32x4 xv0 = *(const f32x4*)(x0 + h);
    f32x4 xv1 = *(const f32x4*)(x1 + h);
#pragma unroll
    for (int a = 0; a < A_SZ; a++){
      f32x4 wv = *(const f32x4*)(swv + a * H_SZ + h);
      acc0[a] += xv0[0]*wv[0] + xv0[1]*wv[1] + xv0[2]*wv[2] + xv0[3]*wv[3];
      acc1[a] += xv1[0]*wv[0] + xv1[1]*wv[1] + xv1[2]*wv[2] + xv1[3]*wv[3];
    }
  }
  float s0 = 0.f, s1 = 0.f;
#pragma unroll
  for (int a = 0; a < A_SZ; a++){
    s0 += sbu[a] * tanh_(acc0[a] + sbv[a]);
    s1 += sbu[a] * tanh_(acc1[a] + sbv[a]);
  }
  int b0 = r0 / tcnt, tc0 = r0 - b0 * tcnt;
  int b1 = r1 / tcnt, tc1 = r1 - b1 * tcnt;
  sc[(size_t)b0 * T_SZ + t0 + tc0] = s0;
  sc[(size_t)b1 * T_SZ + t0 + tc1] = s1;
}

// ---------- online (unnormalized) context accumulation ----------
__global__ __launch_bounds__(256, 1) void attn_acc(
    const float* __restrict__ outi, const float* __restrict__ sc,
    int t0, int tcnt, float* __restrict__ ctx, float* __restrict__ lsum)
{
  int b = blockIdx.x, tid = threadIdx.x;
  float acc = ctx[(size_t)b * H_SZ + tid];
  const float* xp = outi + (size_t)b * tcnt * H_SZ + tid;
  float ls = 0.f;
  for (int tc = 0; tc < tcnt; tc++){
    float e = __expf(sc[(size_t)b * T_SZ + t0 + tc]);
    acc += e * xp[(size_t)tc * H_SZ];
    ls += e;
  }
  ctx[(size_t)b * H_SZ + tid] = acc;
  if (tid == 0) lsum[b] += ls;
}

__global__ __launch_bounds__(256, 1) void attn_fin(
    const float* __restrict__ ctx, const float* __restrict__ lsum,
    float* __restrict__ out)
{
  int b = blockIdx.x, tid = threadIdx.x;
  out[(size_t)b * H_SZ + tid] = ctx[(size_t)b * H_SZ + tid] / lsum[b];
}

// ---------- host ----------
extern "C" void kernel_launch(void* const* d_in, const int* in_sizes, int n_in,
                              void* d_out, int out_size, void* d_ws, size_t ws_size,
                              hipStream_t stream)
{
  (void)in_sizes; (void)n_in; (void)out_size;
  const float* crime = (const float*)d_in[0];
  const float* anom  = (const float*)d_in[1];
  const float* WihC = (const float*)d_in[2];
  const float* WhhC = (const float*)d_in[3];
  const float* bihC = (const float*)d_in[4];
  const float* bhhC = (const float*)d_in[5];
  const float* WihA = (const float*)d_in[6];
  const float* WhhA = (const float*)d_in[7];
  const float* bihA = (const float*)d_in[8];
  const float* bhhA = (const float*)d_in[9];
  const float* WihI = (const float*)d_in[10];
  const float* WhhI = (const float*)d_in[11];
  const float* bihI = (const float*)d_in[12];
  const float* bhhI = (const float*)d_in[13];
  const float* Wv = (const float*)d_in[14];
  const float* bv = (const float*)d_in[15];
  const float* wu = (const float*)d_in[16];
  float* out = (float*)d_out;

  char* ws = (char*)d_ws;
  size_t off = 0;
  auto take = [&](size_t n){ size_t r = off; off += (n + 255) & ~(size_t)255; return r; };

  short* pIhC = (short*)(ws + take((size_t)G3 * 128 * 2));
  short* pHhC = (short*)(ws + take((size_t)G3 * 256 * 2));
  short* pIhA = (short*)(ws + take((size_t)G3 * 96 * 2));
  short* pHhA = (short*)(ws + take((size_t)G3 * 256 * 2));
  short* pIhI = (short*)(ws + take((size_t)G3 * 512 * 2));
  short* pHhI = (short*)(ws + take((size_t)G3 * 256 * 2));
  float* scores = (float*)(ws + take((size_t)B_SZ * T_SZ * 4));

  size_t state_off = off;
  float* hsC  = (float*)(ws + take((size_t)B_SZ * H_SZ * 4));
  float* hsA  = (float*)(ws + take((size_t)B_SZ * H_SZ * 4));
  float* hsI  = (float*)(ws + take((size_t)B_SZ * H_SZ * 4));
  float* ctx  = (float*)(ws + take((size_t)B_SZ * H_SZ * 4));
  float* lsum = (float*)(ws + take((size_t)B_SZ * 4));
  size_t state_end = off;

  // adaptive T-chunk: Gi(768) + Oca(512) + Oi(256) per timestep
  size_t per = (size_t)B_SZ * 4 * (G3 + 512 + H_SZ);   // 12.58 MB per timestep
  size_t avail = (ws_size > off + 4096) ? (ws_size - off - 4096) : 0;
  int TC = (int)(avail / per);
  if (TC < 1) TC = 1;
  if (TC > T_SZ) TC = T_SZ;

  float* Gi  = (float*)(ws + take((size_t)B_SZ * TC * G3 * 4));
  float* Oca = (float*)(ws + take((size_t)B_SZ * TC * 512 * 4));
  float* Oi  = (float*)(ws + take((size_t)B_SZ * TC * H_SZ * 4));

  // zero h-states, ctx, lsum (every launch: deterministic)
  zinit<<<2048, 256, 0, stream>>>((float*)(ws + state_off), (state_end - state_off) / 4);

  // pack weights (bf16 hi bricks)
  packw_h<<<48 * 4,  64, 0, stream>>>(WihC, 128, pIhC);
  packw_h<<<48 * 8,  64, 0, stream>>>(WhhC, 256, pHhC);
  packw_h<<<48 * 3,  64, 0, stream>>>(WihA,  96, pIhA);
  packw_h<<<48 * 8,  64, 0, stream>>>(WhhA, 256, pHhA);
  packw_h<<<48 * 16, 64, 0, stream>>>(WihI, 512, pIhI);
  packw_h<<<48 * 8,  64, 0, stream>>>(WhhI, 256, pHhI);

  for (int t0 = 0; t0 < T_SZ; ){
    int tcnt = T_SZ - t0 < TC ? T_SZ - t0 : TC;
    int rows = B_SZ * tcnt;
    // fused leaf GRUs (ih + hh): 512 WGs of 8 rows -> 2 blocks/CU
    gru_leaf<<<512, 512, 0, stream>>>(
        crime, pIhC, pHhC, bihC, bhhC, Oca, 0,   hsC,
        anom,  pIhA, pHhA, bihA, bhhA, Oca, 256, hsA,
        256, t0, tcnt);
    // inter projection + recurrence (256 WGs of 8 rows = full GPU)
    gemm2p<<<rows / 64, 512, 0, stream>>>(Oca, 512, 0, 0, tcnt,
                                          pIhI, bihI, bhhI, Gi);
    gru_inter<<<256, 512, 0, stream>>>(Gi, pHhI, bhhI, Oi, hsI, tcnt);
    // attention: scores + online context accumulation
    attn_scores<<<rows / 512, 256, 0, stream>>>(Oi, Wv, bv, wu, scores, t0, tcnt);
    attn_acc<<<B_SZ, 256, 0, stream>>>(Oi, scores, t0, tcnt, ctx, lsum);
    t0 += tcnt;
  }
  attn_fin<<<B_SZ, 256, 0, stream>>>(ctx, lsum, out);
}

// Round 10
// 4593.983 us; speedup vs baseline: 2.1717x; 2.1717x over previous
//
#include <hip/hip_runtime.h>

// ---------- types ----------
typedef float  f32x4  __attribute__((ext_vector_type(4)));
typedef short  short8 __attribute__((ext_vector_type(8)));
typedef __bf16 bf16x8 __attribute__((ext_vector_type(8)));

#define B_SZ 2048
#define T_SZ 120
#define H_SZ 256
#define G3   768      // 3H
#define A_SZ 40

#define MFMA_BF16 __builtin_amdgcn_mfma_f32_16x16x32_bf16

union U8 { short8 s; bf16x8 b; };
__device__ __forceinline__ bf16x8 as_bf(short8 s){ U8 u; u.s = s; return u.b; }

__device__ __forceinline__ unsigned short f2bf(float x){
  unsigned u = __float_as_uint(x);
  return (unsigned short)((u + 0x7FFFu + ((u >> 16) & 1u)) >> 16);
}
__device__ __forceinline__ float bf2f(unsigned short h){
  return __uint_as_float(((unsigned)h) << 16);
}
__device__ __forceinline__ void cvt_hilo(float x, short& hi, short& lo){
  unsigned short h = f2bf(x);
  hi = (short)h;
  lo = (short)f2bf(x - bf2f(h));
}
__device__ __forceinline__ float sigm(float x){ return 1.0f / (1.0f + __expf(-x)); }
__device__ __forceinline__ float tanh_(float x){
  float a = fabsf(x);
  float t = 1.0f - 2.0f / (__expf(2.0f * a) + 1.0f);
  return copysignf(t, x);
}

// ---------- zero-init scratch state ----------
__global__ void zinit(float* __restrict__ p, size_t n){
  size_t i = (size_t)blockIdx.x * 256 + threadIdx.x;
  size_t stride = (size_t)gridDim.x * 256;
  for (; i < n; i += stride) p[i] = 0.0f;
}

// ---------- single packing kernel: all 6 weight brick sets + WvT bricks ----------
// standard brick: pack[((nt*KT+kt)*64+lane)*8+i] = W[nt*16+lane%16][kt*32+(lane/16)*8+i]
__global__ void packall(const float* __restrict__ WihC, const float* __restrict__ WhhC,
                        const float* __restrict__ WihA, const float* __restrict__ WhhA,
                        const float* __restrict__ WihI, const float* __restrict__ WhhI,
                        const float* __restrict__ Wv,
                        short* __restrict__ pIhC, short* __restrict__ pHhC,
                        short* __restrict__ pIhA, short* __restrict__ pHhA,
                        short* __restrict__ pIhI, short* __restrict__ pHhI,
                        short* __restrict__ pWvT)
{
  int b = blockIdx.x;
  int lane = threadIdx.x;
  const float* src; short* dst; int K;
  if      (b < 192)  { src = WihC; dst = pIhC; K = 128; }
  else if (b < 576)  { b -= 192;  src = WhhC; dst = pHhC; K = 256; }
  else if (b < 720)  { b -= 576;  src = WihA; dst = pIhA; K = 96;  }
  else if (b < 1104) { b -= 720;  src = WhhA; dst = pHhA; K = 256; }
  else if (b < 1872) { b -= 1104; src = WihI; dst = pIhI; K = 512; }
  else if (b < 2256) { b -= 1872; src = WhhI; dst = pHhI; K = 256; }
  else {
    // WvT bricks: b-2256 in [0,24): q = ntile (cols a), kt
    int bb = b - 2256;
    int q = bb >> 3, kt = bb & 7;
    int a = q * 16 + (lane & 15);
    int k = kt * 32 + (lane >> 4) * 8;
    size_t o = (((size_t)q * 8 + kt) * 64 + lane) * 8;
#pragma unroll
    for (int i = 0; i < 8; i++){
      float v = (a < A_SZ) ? Wv[(size_t)a * H_SZ + k + i] : 0.0f;
      pWvT[o + i] = (short)f2bf(v);
    }
    return;
  }
  int KT = K >> 5;
  int nt = b / KT, kt = b % KT;
  const float* s = src + (size_t)(nt * 16 + (lane & 15)) * K + kt * 32 + (lane >> 4) * 8;
  size_t o = (((size_t)nt * KT + kt) * 64 + lane) * 8;
#pragma unroll
  for (int i = 0; i < 8; i++) dst[o + i] = (short)f2bf(s[i]);
}

// ---------- input-projection GEMM (inter): 2-pass (A split hi/lo, B hi) ----------
__global__ __launch_bounds__(512, 1) void gemm2p(
    const float* __restrict__ A, int K, int rowT, int t0, int tcnt,
    const short* __restrict__ Bhi,
    const float* __restrict__ b1, const float* __restrict__ b2,
    float* __restrict__ C)
{
  int tid = threadIdx.x;
  int w = tid >> 6, lane = tid & 63;
  int mg = w & 1, ng = w >> 1;         // ng 0..3
  int m0 = blockIdx.x * 64 + mg * 32;
  int nb = ng * 12;
  int KT = K >> 5;
  const f32x4 zero = {0.f, 0.f, 0.f, 0.f};
  f32x4 acc[2][12];
#pragma unroll
  for (int f = 0; f < 2; f++)
#pragma unroll
    for (int q = 0; q < 12; q++) acc[f][q] = zero;

  int rr = lane & 15, ks = lane >> 4;
  const float* Ap[2];
#pragma unroll
  for (int f = 0; f < 2; f++){
    int r = m0 + f * 16 + rr;
    size_t ar;
    if (rowT){
      int b = r / tcnt;
      int tc = r - b * tcnt;
      ar = (size_t)b * rowT + t0 + tc;
    } else {
      ar = (size_t)r;
    }
    Ap[f] = A + ar * K + ks * 8;
  }

  for (int kt = 0; kt < KT; ++kt){
    bf16x8 ahb[2], alb[2];
#pragma unroll
    for (int f = 0; f < 2; f++){
      f32x4 a0 = *(const f32x4*)(Ap[f] + kt * 32);
      f32x4 a1 = *(const f32x4*)(Ap[f] + kt * 32 + 4);
      short8 ah, al;
#pragma unroll
      for (int i = 0; i < 4; i++){
        short h, l;
        cvt_hilo(a0[i], h, l); ah[i] = h;   al[i] = l;
        cvt_hilo(a1[i], h, l); ah[i+4] = h; al[i+4] = l;
      }
      ahb[f] = as_bf(ah); alb[f] = as_bf(al);
    }
#pragma unroll
    for (int q = 0; q < 12; q++){
      int bo = (((nb + q) * KT + kt) * 64 + lane) * 8;
      bf16x8 bh = as_bf(*(const short8*)(Bhi + bo));
#pragma unroll
      for (int f = 0; f < 2; f++){
        acc[f][q] = MFMA_BF16(ahb[f], bh, acc[f][q], 0, 0, 0);
        acc[f][q] = MFMA_BF16(alb[f], bh, acc[f][q], 0, 0, 0);
      }
    }
  }
  int nc = lane & 15;
  int rb = lane >> 4;
#pragma unroll
  for (int q = 0; q < 12; q++){
    int n = (nb + q) * 16 + nc;
    float bias = b1[n] + (n < 512 ? b2[n] : 0.0f);
#pragma unroll
    for (int f = 0; f < 2; f++)
#pragma unroll
      for (int i = 0; i < 4; i++)
        C[(size_t)(m0 + f * 16 + rb * 4 + i) * G3 + n] = acc[f][q][i] + bias;
  }
}

// ---------- fused leaf GRU: 16 rows/WG (R6 config), gates in registers ----------
template<int D, int KI>
__device__ __forceinline__ void leaf_body(
    const float* __restrict__ x, const short* __restrict__ Wih,
    const short* __restrict__ Whh, const float* __restrict__ bih,
    const float* __restrict__ bhh, float* __restrict__ outp, int ooff,
    float* __restrict__ hs, int b0, int t0, int tcnt,
    short* hhi, short* hlo, short* xhi)
{
  constexpr int XP  = D + 8;
  constexpr int NST = 2 * D;
  constexpr int CPR = D / 8;
  int tid = threadIdx.x, w = tid >> 6, lane = tid & 63;
  int arow = lane & 15, kgrp = lane >> 4;
  int c0 = w * 16 + arow;
  int msk = (arow & 7) << 4;

  float bir[2], biz[2], bin_[2], bhn[2];
#pragma unroll
  for (int j = 0; j < 2; j++){
    int c = c0 + j * 128;
    bir[j] = bih[c] + bhh[c];
    biz[j] = bih[256 + c] + bhh[256 + c];
    bin_[j] = bih[512 + c];
    bhn[j] = bhh[512 + c];
  }

  int srow = tid / CPR, scol = (tid % CPR) * 8;
  bool stg = tid < NST;
  const float* sx = x + ((size_t)(b0 + srow) * T_SZ + t0) * D + scol;
  short* xwh = xhi + srow * XP + scol;

  float hreg[2][4];
#pragma unroll
  for (int j = 0; j < 2; j++)
#pragma unroll
  for (int i = 0; i < 4; i++){
    int row = kgrp * 4 + i, c = c0 + j * 128;
    float v = hs[(size_t)(b0 + row) * H_SZ + c];
    hreg[j][i] = v;
    short h_, l_; cvt_hilo(v, h_, l_);
    int off = row * 512 + ((c * 2) ^ ((row & 7) << 4));
    *(short*)((char*)hhi + off) = h_;
    *(short*)((char*)hlo + off) = l_;
  }
  if (stg){
    f32x4 a0 = *(const f32x4*)sx;
    f32x4 a1 = *(const f32x4*)(sx + 4);
    short8 h8;
#pragma unroll
    for (int i = 0; i < 4; i++){ h8[i] = (short)f2bf(a0[i]); h8[4+i] = (short)f2bf(a1[i]); }
    *(short8*)xwh = h8;
  }
  __syncthreads();

  short8 whr[5][6];
#pragma unroll
  for (int kt = 0; kt < 5; kt++)
#pragma unroll
    for (int q = 0; q < 6; q++)
      whr[kt][q] = *(const short8*)(Whh + (((w + 8 * q) * 8 + kt) * 64 + lane) * 8);

  const char* hhp = (const char*)hhi + arow * 512;
  const char* hlp = (const char*)hlo + arow * 512;
  const char* xhp = (const char*)xhi + (arow * XP + kgrp * 8) * 2;

  const f32x4 zero = {0.f, 0.f, 0.f, 0.f};
  for (int t = 0; t < tcnt; t++){
    f32x4 acc[6], accNi[2];
#pragma unroll
    for (int q = 0; q < 6; q++) acc[q] = zero;
    accNi[0] = zero; accNi[1] = zero;

    short8 wb[6], wn[6];
#pragma unroll
    for (int q = 0; q < 6; q++)
      wb[q] = *(const short8*)(Wih + (((w + 8 * q) * KI) * 64 + lane) * 8);
#pragma unroll
    for (int kt = 0; kt < KI; kt++){
      if (kt + 1 < KI){
#pragma unroll
        for (int q = 0; q < 6; q++)
          wn[q] = *(const short8*)(Wih + (((w + 8 * q) * KI + kt + 1) * 64 + lane) * 8);
      }
      bf16x8 ah = as_bf(*(const short8*)(xhp + kt * 64));
#pragma unroll
      for (int q = 0; q < 6; q++){
        bf16x8 bw = as_bf(wb[q]);
        if (q < 4) acc[q] = MFMA_BF16(ah, bw, acc[q], 0, 0, 0);
        else       accNi[q-4] = MFMA_BF16(ah, bw, accNi[q-4], 0, 0, 0);
      }
      if (kt + 1 < KI){
#pragma unroll
        for (int q = 0; q < 6; q++) wb[q] = wn[q];
      }
    }
#pragma unroll
    for (int q = 0; q < 6; q++)
      wb[q] = *(const short8*)(Whh + (((w + 8 * q) * 8 + 5) * 64 + lane) * 8);
#pragma unroll
    for (int kt = 0; kt < 5; kt++){
      int kb = (kt * 64 + kgrp * 16) ^ msk;
      bf16x8 ah = as_bf(*(const short8*)(hhp + kb));
      bf16x8 al = as_bf(*(const short8*)(hlp + kb));
#pragma unroll
      for (int q = 0; q < 6; q++){
        bf16x8 bw = as_bf(whr[kt][q]);
        acc[q] = MFMA_BF16(ah, bw, acc[q], 0, 0, 0);
        acc[q] = MFMA_BF16(al, bw, acc[q], 0, 0, 0);
      }
    }
#pragma unroll
    for (int kt = 5; kt < 8; kt++){
      if (kt < 7){
#pragma unroll
        for (int q = 0; q < 6; q++)
          wn[q] = *(const short8*)(Whh + (((w + 8 * q) * 8 + kt + 1) * 64 + lane) * 8);
      }
      int kb = (kt * 64 + kgrp * 16) ^ msk;
      bf16x8 ah = as_bf(*(const short8*)(hhp + kb));
      bf16x8 al = as_bf(*(const short8*)(hlp + kb));
#pragma unroll
      for (int q = 0; q < 6; q++){
        bf16x8 bw = as_bf(wb[q]);
        acc[q] = MFMA_BF16(ah, bw, acc[q], 0, 0, 0);
        acc[q] = MFMA_BF16(al, bw, acc[q], 0, 0, 0);
      }
      if (kt < 7){
#pragma unroll
        for (int q = 0; q < 6; q++) wb[q] = wn[q];
      }
    }
    __syncthreads();   // b1

    f32x4 a0, a1;
    bool ds = stg && (t + 1 < tcnt);
    if (ds){
      a0 = *(const f32x4*)(sx + (size_t)(t + 1) * D);
      a1 = *(const f32x4*)(sx + (size_t)(t + 1) * D + 4);
    }

#pragma unroll
    for (int j = 0; j < 2; j++)
#pragma unroll
    for (int i = 0; i < 4; i++){
      float rr = sigm(acc[j][i] + bir[j]);
      float zz = sigm(acc[2 + j][i] + biz[j]);
      float nn = tanh_(accNi[j][i] + bin_[j] + rr * (acc[4 + j][i] + bhn[j]));
      float hv = (1.0f - zz) * nn + zz * hreg[j][i];
      hreg[j][i] = hv;
      int row = kgrp * 4 + i, c = c0 + j * 128;
      outp[((size_t)(b0 + row) * tcnt + t) * 512 + ooff + c] = hv;
      short h_, l_; cvt_hilo(hv, h_, l_);
      int off = row * 512 + ((c * 2) ^ ((row & 7) << 4));
      *(short*)((char*)hhi + off) = h_;
      *(short*)((char*)hlo + off) = l_;
    }
    if (ds){
      short8 h8;
#pragma unroll
      for (int i = 0; i < 4; i++){ h8[i] = (short)f2bf(a0[i]); h8[4+i] = (short)f2bf(a1[i]); }
      *(short8*)xwh = h8;
    }
    __syncthreads();   // b2
  }

#pragma unroll
  for (int j = 0; j < 2; j++)
#pragma unroll
  for (int i = 0; i < 4; i++){
    int row = kgrp * 4 + i;
    hs[(size_t)(b0 + row) * H_SZ + c0 + j * 128] = hreg[j][i];
  }
}

__global__ __launch_bounds__(512, 2) void gru_leaf(
    const float* __restrict__ x0, const short* __restrict__ Wih0,
    const short* __restrict__ Whh0, const float* __restrict__ bih0,
    const float* __restrict__ bhh0, float* __restrict__ out0, int ooff0,
    float* __restrict__ hs0,
    const float* __restrict__ x1, const short* __restrict__ Wih1,
    const short* __restrict__ Whh1, const float* __restrict__ bih1,
    const float* __restrict__ bhh1, float* __restrict__ out1, int ooff1,
    float* __restrict__ hs1,
    int nwg0, int t0, int tcnt)
{
  __shared__ short hhi[16 * 256];
  __shared__ short hlo[16 * 256];
  __shared__ short xhi[16 * 136];
  if ((int)blockIdx.x < nwg0)
    leaf_body<128, 4>(x0, Wih0, Whh0, bih0, bhh0, out0, ooff0, hs0,
                      blockIdx.x * 16, t0, tcnt, hhi, hlo, xhi);
  else
    leaf_body<96, 3>(x1, Wih1, Whh1, bih1, bhh1, out1, ooff1, hs1,
                     (blockIdx.x - nwg0) * 16, t0, tcnt, hhi, hlo, xhi);
}

// ---------- inter GRU: 16 rows/WG, gi precomputed, uniform 8-kt W ring ----------
__global__ __launch_bounds__(512, 2) void gru_inter(
    const float* __restrict__ gi,
    const short* __restrict__ Whh, const float* __restrict__ bhh,
    float* __restrict__ outp, float* __restrict__ hs, int tcnt)
{
  __shared__ short hhi[16 * 256];
  __shared__ short hlo[16 * 256];
  int b0 = blockIdx.x * 16;
  int tid = threadIdx.x, w = tid >> 6, lane = tid & 63;
  int arow = lane & 15, kgrp = lane >> 4;
  int c0 = w * 16 + arow;
  int msk = (arow & 7) << 4;

  float bhn[2];
  bhn[0] = bhh[512 + c0];
  bhn[1] = bhh[512 + c0 + 128];

  float hreg[2][4];
#pragma unroll
  for (int j = 0; j < 2; j++)
#pragma unroll
  for (int i = 0; i < 4; i++){
    int row = kgrp * 4 + i, c = c0 + j * 128;
    float v = hs[(size_t)(b0 + row) * H_SZ + c];
    hreg[j][i] = v;
    short h_, l_; cvt_hilo(v, h_, l_);
    int off = row * 512 + ((c * 2) ^ ((row & 7) << 4));
    *(short*)((char*)hhi + off) = h_;
    *(short*)((char*)hlo + off) = l_;
  }
  __syncthreads();

  const char* hhp = (const char*)hhi + arow * 512;
  const char* hlp = (const char*)hlo + arow * 512;
  const float* gp[4];
#pragma unroll
  for (int i = 0; i < 4; i++)
    gp[i] = gi + (size_t)(b0 + kgrp * 4 + i) * tcnt * G3;

  const f32x4 zero = {0.f, 0.f, 0.f, 0.f};
  for (int t = 0; t < tcnt; t++){
    float gvr[2][4], gvz[2][4], gvn[2][4];
#pragma unroll
    for (int j = 0; j < 2; j++)
#pragma unroll
    for (int i = 0; i < 4; i++){
      const float* g = gp[i] + (size_t)t * G3 + c0 + j * 128;
      gvr[j][i] = g[0];
      gvz[j][i] = g[256];
      gvn[j][i] = g[512];
    }

    f32x4 acc[6];
#pragma unroll
    for (int q = 0; q < 6; q++) acc[q] = zero;

    short8 wb[6], wn[6];
#pragma unroll
    for (int q = 0; q < 6; q++)
      wb[q] = *(const short8*)(Whh + (((w + 8 * q) * 8) * 64 + lane) * 8);
#pragma unroll
    for (int kt = 0; kt < 8; kt++){
      if (kt < 7){
#pragma unroll
        for (int q = 0; q < 6; q++)
          wn[q] = *(const short8*)(Whh + (((w + 8 * q) * 8 + kt + 1) * 64 + lane) * 8);
      }
      int kb = (kt * 64 + kgrp * 16) ^ msk;
      bf16x8 ah = as_bf(*(const short8*)(hhp + kb));
      bf16x8 al = as_bf(*(const short8*)(hlp + kb));
#pragma unroll
      for (int q = 0; q < 6; q++){
        bf16x8 bw = as_bf(wb[q]);
        acc[q] = MFMA_BF16(ah, bw, acc[q], 0, 0, 0);
        acc[q] = MFMA_BF16(al, bw, acc[q], 0, 0, 0);
      }
      if (kt < 7){
#pragma unroll
        for (int q = 0; q < 6; q++) wb[q] = wn[q];
      }
    }
    __syncthreads();   // b1

#pragma unroll
    for (int j = 0; j < 2; j++)
#pragma unroll
    for (int i = 0; i < 4; i++){
      float rr = sigm(gvr[j][i] + acc[j][i]);
      float zz = sigm(gvz[j][i] + acc[2 + j][i]);
      float nn = tanh_(gvn[j][i] + rr * (acc[4 + j][i] + bhn[j]));
      float hv = (1.0f - zz) * nn + zz * hreg[j][i];
      hreg[j][i] = hv;
      int row = kgrp * 4 + i, c = c0 + j * 128;
      outp[((size_t)(b0 + row) * tcnt + t) * H_SZ + c] = hv;
      short h_, l_; cvt_hilo(hv, h_, l_);
      int off = row * 512 + ((c * 2) ^ ((row & 7) << 4));
      *(short*)((char*)hhi + off) = h_;
      *(short*)((char*)hlo + off) = l_;
    }
    __syncthreads();   // b2
  }

#pragma unroll
  for (int j = 0; j < 2; j++)
#pragma unroll
  for (int i = 0; i < 4; i++){
    int row = kgrp * 4 + i;
    hs[(size_t)(b0 + row) * H_SZ + c0 + j * 128] = hreg[j][i];
  }
}

// ---------- fused attention: per-batch block, MFMA scores + online exp-ctx ----------
// um[t][a] via mfma(A = x rows bf16-hi, B = WvT bricks); s = wu . tanh(um + bv);
// ctx += e^s * x (unnormalized; |s| <= sum|wu| ~ 1.6 so exp is safe).
__global__ __launch_bounds__(256, 4) void attn_fused(
    const float* __restrict__ outi,   // [B*tcnt, 256] chunk-local
    const short* __restrict__ WvT,    // 3 ntiles x 8 kts x 64 x 8
    const float* __restrict__ bv, const float* __restrict__ wu,
    float* __restrict__ ctx, float* __restrict__ lsum, int tcnt)
{
  __shared__ float ctxsh[4][256];
  __shared__ float lssh[4];
  int b = blockIdx.x;
  int tid = threadIdx.x, wv = tid >> 6, lane = tid & 63;
  int colc = lane & 15, rgrp = lane >> 4;

  float wuv[3], bvv[3];
#pragma unroll
  for (int q = 0; q < 3; q++){
    int a = q * 16 + colc;
    wuv[q] = (a < A_SZ) ? wu[a] : 0.0f;
    bvv[q] = (a < A_SZ) ? bv[a] : 0.0f;
  }

  const float* xb = outi + (size_t)b * tcnt * H_SZ;
  f32x4 ctx4 = {0.f, 0.f, 0.f, 0.f};
  float ls = 0.f;
  const f32x4 zero = {0.f, 0.f, 0.f, 0.f};

  int nchunk = (tcnt + 15) >> 4;
  for (int c = wv; c < nchunk; c += 4){
    int tbase = c << 4;
    // scores MFMA: A rows = 16 timesteps
    f32x4 um[3];
#pragma unroll
    for (int q = 0; q < 3; q++) um[q] = zero;
    int trow = tbase + colc;
    int tr = trow < tcnt ? trow : tcnt - 1;
    const float* ap = xb + (size_t)tr * H_SZ + rgrp * 8;
#pragma unroll
    for (int kt = 0; kt < 8; kt++){
      f32x4 a0 = *(const f32x4*)(ap + kt * 32);
      f32x4 a1 = *(const f32x4*)(ap + kt * 32 + 4);
      short8 ah;
#pragma unroll
      for (int i = 0; i < 4; i++){ ah[i] = (short)f2bf(a0[i]); ah[4+i] = (short)f2bf(a1[i]); }
      bf16x8 ahb = as_bf(ah);
#pragma unroll
      for (int q = 0; q < 3; q++){
        bf16x8 bw = as_bf(*(const short8*)(WvT + ((q * 8 + kt) * 64 + lane) * 8));
        um[q] = MFMA_BF16(ahb, bw, um[q], 0, 0, 0);
      }
    }
    // per-lane partial score for rows rgrp*4+i
    f32x4 sp;
#pragma unroll
    for (int i = 0; i < 4; i++){
      float v = 0.f;
#pragma unroll
      for (int q = 0; q < 3; q++)
        v += wuv[q] * tanh_(um[q][i] + bvv[q]);
      sp[i] = v;
    }
    // reduce across 16 lanes of the row group
#pragma unroll
    for (int d = 1; d < 16; d <<= 1){
#pragma unroll
      for (int i = 0; i < 4; i++)
        sp[i] += __shfl_xor(sp[i], d);
    }
    f32x4 e4;
#pragma unroll
    for (int i = 0; i < 4; i++){
      int t = tbase + rgrp * 4 + i;
      e4[i] = (t < tcnt) ? __expf(sp[i]) : 0.0f;
      ls += e4[i];   // per-lane: covers its group's rows; groups combined at end
    }
    // ctx accumulation: lane owns cols lane*4..+3
#pragma unroll
    for (int r = 0; r < 16; r++){
      float e = __shfl(e4[r & 3], (r >> 2) << 4);
      int t = tbase + r;
      int tcl = t < tcnt ? t : tcnt - 1;
      f32x4 x4 = *(const f32x4*)(xb + (size_t)tcl * H_SZ + lane * 4);
      ctx4 += e * x4;
    }
  }
  // combine the 4 row-groups' ls (each group's value identical within group)
  ls += __shfl_xor(ls, 16);
  ls += __shfl_xor(ls, 32);

  *(f32x4*)&ctxsh[wv][lane * 4] = ctx4;
  if (lane == 0) lssh[wv] = ls;
  __syncthreads();
  float cv = ctxsh[0][tid] + ctxsh[1][tid] + ctxsh[2][tid] + ctxsh[3][tid];
  ctx[(size_t)b * H_SZ + tid] += cv;
  if (tid == 0) lsum[b] += lssh[0] + lssh[1] + lssh[2] + lssh[3];
}

__global__ __launch_bounds__(256, 1) void attn_fin(
    const float* __restrict__ ctx, const float* __restrict__ lsum,
    float* __restrict__ out)
{
  int b = blockIdx.x, tid = threadIdx.x;
  out[(size_t)b * H_SZ + tid] = ctx[(size_t)b * H_SZ + tid] / lsum[b];
}

// ---------- host ----------
extern "C" void kernel_launch(void* const* d_in, const int* in_sizes, int n_in,
                              void* d_out, int out_size, void* d_ws, size_t ws_size,
                              hipStream_t stream)
{
  (void)in_sizes; (void)n_in; (void)out_size;
  const float* crime = (const float*)d_in[0];
  const float* anom  = (const float*)d_in[1];
  const float* WihC = (const float*)d_in[2];
  const float* WhhC = (const float*)d_in[3];
  const float* bihC = (const float*)d_in[4];
  const float* bhhC = (const float*)d_in[5];
  const float* WihA = (const float*)d_in[6];
  const float* WhhA = (const float*)d_in[7];
  const float* bihA = (const float*)d_in[8];
  const float* bhhA = (const float*)d_in[9];
  const float* WihI = (const float*)d_in[10];
  const float* WhhI = (const float*)d_in[11];
  const float* bihI = (const float*)d_in[12];
  const float* bhhI = (const float*)d_in[13];
  const float* Wv = (const float*)d_in[14];
  const float* bv = (const float*)d_in[15];
  const float* wu = (const float*)d_in[16];
  float* out = (float*)d_out;

  char* ws = (char*)d_ws;
  size_t off = 0;
  auto take = [&](size_t n){ size_t r = off; off += (n + 255) & ~(size_t)255; return r; };

  short* pIhC = (short*)(ws + take((size_t)G3 * 128 * 2));
  short* pHhC = (short*)(ws + take((size_t)G3 * 256 * 2));
  short* pIhA = (short*)(ws + take((size_t)G3 * 96 * 2));
  short* pHhA = (short*)(ws + take((size_t)G3 * 256 * 2));
  short* pIhI = (short*)(ws + take((size_t)G3 * 512 * 2));
  short* pHhI = (short*)(ws + take((size_t)G3 * 256 * 2));
  short* pWvT = (short*)(ws + take((size_t)3 * 8 * 64 * 8 * 2));

  size_t state_off = off;
  float* hsC  = (float*)(ws + take((size_t)B_SZ * H_SZ * 4));
  float* hsA  = (float*)(ws + take((size_t)B_SZ * H_SZ * 4));
  float* hsI  = (float*)(ws + take((size_t)B_SZ * H_SZ * 4));
  float* ctx  = (float*)(ws + take((size_t)B_SZ * H_SZ * 4));
  float* lsum = (float*)(ws + take((size_t)B_SZ * 4));
  size_t state_end = off;

  // adaptive T-chunk: Gi(768) + Oca(512) + Oi(256) per timestep
  size_t per = (size_t)B_SZ * 4 * (G3 + 512 + H_SZ);   // 12.58 MB per timestep
  size_t avail = (ws_size > off + 4096) ? (ws_size - off - 4096) : 0;
  int TC = (int)(avail / per);
  if (TC < 1) TC = 1;
  if (TC > T_SZ) TC = T_SZ;

  float* Gi  = (float*)(ws + take((size_t)B_SZ * TC * G3 * 4));
  float* Oca = (float*)(ws + take((size_t)B_SZ * TC * 512 * 4));
  float* Oi  = (float*)(ws + take((size_t)B_SZ * TC * H_SZ * 4));

  // zero h-states, ctx, lsum (every launch: deterministic)
  zinit<<<2048, 256, 0, stream>>>((float*)(ws + state_off), (state_end - state_off) / 4);

  // pack all weight bricks + WvT in one dispatch (2280 blocks)
  packall<<<2280, 64, 0, stream>>>(WihC, WhhC, WihA, WhhA, WihI, WhhI, Wv,
                                   pIhC, pHhC, pIhA, pHhA, pIhI, pHhI, pWvT);

  for (int t0 = 0; t0 < T_SZ; ){
    int tcnt = T_SZ - t0 < TC ? T_SZ - t0 : TC;
    int rows = B_SZ * tcnt;
    // fused leaf GRUs (ih + hh): 256 WGs = all CUs
    gru_leaf<<<256, 512, 0, stream>>>(
        crime, pIhC, pHhC, bihC, bhhC, Oca, 0,   hsC,
        anom,  pIhA, pHhA, bihA, bhhA, Oca, 256, hsA,
        128, t0, tcnt);
    // inter projection + recurrence
    gemm2p<<<rows / 64, 512, 0, stream>>>(Oca, 512, 0, 0, tcnt,
                                          pIhI, bihI, bhhI, Gi);
    gru_inter<<<128, 512, 0, stream>>>(Gi, pHhI, bhhI, Oi, hsI, tcnt);
    // fused attention (scores + online context)
    attn_fused<<<B_SZ, 256, 0, stream>>>(Oi, pWvT, bv, wu, ctx, lsum, tcnt);
    t0 += tcnt;
  }
  attn_fin<<<B_SZ, 256, 0, stream>>>(ctx, lsum, out);
}

// Round 11
// 4057.628 us; speedup vs baseline: 2.4588x; 1.1322x over previous
//
#include <hip/hip_runtime.h>

// ---------- types ----------
typedef float  f32x4  __attribute__((ext_vector_type(4)));
typedef short  short8 __attribute__((ext_vector_type(8)));
typedef __bf16 bf16x8 __attribute__((ext_vector_type(8)));

#define B_SZ 2048
#define T_SZ 120
#define H_SZ 256
#define G3   768      // 3H
#define A_SZ 40

#define MFMA_BF16 __builtin_amdgcn_mfma_f32_16x16x32_bf16

union U8 { short8 s; bf16x8 b; };
__device__ __forceinline__ bf16x8 as_bf(short8 s){ U8 u; u.s = s; return u.b; }

__device__ __forceinline__ unsigned short f2bf(float x){
  unsigned u = __float_as_uint(x);
  return (unsigned short)((u + 0x7FFFu + ((u >> 16) & 1u)) >> 16);
}
__device__ __forceinline__ float bf2f(unsigned short h){
  return __uint_as_float(((unsigned)h) << 16);
}
__device__ __forceinline__ void cvt_hilo(float x, short& hi, short& lo){
  unsigned short h = f2bf(x);
  hi = (short)h;
  lo = (short)f2bf(x - bf2f(h));
}
__device__ __forceinline__ float sigm(float x){ return 1.0f / (1.0f + __expf(-x)); }
__device__ __forceinline__ float tanh_(float x){
  float a = fabsf(x);
  float t = 1.0f - 2.0f / (__expf(2.0f * a) + 1.0f);
  return copysignf(t, x);
}

// ---------- zero-init scratch state ----------
__global__ void zinit(float* __restrict__ p, size_t n){
  size_t i = (size_t)blockIdx.x * 256 + threadIdx.x;
  size_t stride = (size_t)gridDim.x * 256;
  for (; i < n; i += stride) p[i] = 0.0f;
}

// ---------- single packing kernel: all 6 weight brick sets + WvT bricks ----------
__global__ void packall(const float* __restrict__ WihC, const float* __restrict__ WhhC,
                        const float* __restrict__ WihA, const float* __restrict__ WhhA,
                        const float* __restrict__ WihI, const float* __restrict__ WhhI,
                        const float* __restrict__ Wv,
                        short* __restrict__ pIhC, short* __restrict__ pHhC,
                        short* __restrict__ pIhA, short* __restrict__ pHhA,
                        short* __restrict__ pIhI, short* __restrict__ pHhI,
                        short* __restrict__ pWvT)
{
  int b = blockIdx.x;
  int lane = threadIdx.x;
  const float* src; short* dst; int K;
  if      (b < 192)  { src = WihC; dst = pIhC; K = 128; }
  else if (b < 576)  { b -= 192;  src = WhhC; dst = pHhC; K = 256; }
  else if (b < 720)  { b -= 576;  src = WihA; dst = pIhA; K = 96;  }
  else if (b < 1104) { b -= 720;  src = WhhA; dst = pHhA; K = 256; }
  else if (b < 1872) { b -= 1104; src = WihI; dst = pIhI; K = 512; }
  else if (b < 2256) { b -= 1872; src = WhhI; dst = pHhI; K = 256; }
  else {
    int bb = b - 2256;
    int q = bb >> 3, kt = bb & 7;
    int a = q * 16 + (lane & 15);
    int k = kt * 32 + (lane >> 4) * 8;
    size_t o = (((size_t)q * 8 + kt) * 64 + lane) * 8;
#pragma unroll
    for (int i = 0; i < 8; i++){
      float v = (a < A_SZ) ? Wv[(size_t)a * H_SZ + k + i] : 0.0f;
      pWvT[o + i] = (short)f2bf(v);
    }
    return;
  }
  int KT = K >> 5;
  int nt = b / KT, kt = b % KT;
  const float* s = src + (size_t)(nt * 16 + (lane & 15)) * K + kt * 32 + (lane >> 4) * 8;
  size_t o = (((size_t)nt * KT + kt) * 64 + lane) * 8;
#pragma unroll
  for (int i = 0; i < 8; i++) dst[o + i] = (short)f2bf(s[i]);
}

// ---------- input-projection GEMM (inter): 1-pass, A = bf16-hi shorts ----------
__global__ __launch_bounds__(512, 1) void gemm1p(
    const short* __restrict__ A,        // [rows, 512] bf16-hi
    const short* __restrict__ Bhi,
    const float* __restrict__ b1, const float* __restrict__ b2,
    float* __restrict__ C)
{
  int tid = threadIdx.x;
  int w = tid >> 6, lane = tid & 63;
  int mg = w & 1, ng = w >> 1;         // ng 0..3
  int m0 = blockIdx.x * 64 + mg * 32;
  int nb = ng * 12;
  const int KT = 16;                   // K = 512
  const f32x4 zero = {0.f, 0.f, 0.f, 0.f};
  f32x4 acc[2][12];
#pragma unroll
  for (int f = 0; f < 2; f++)
#pragma unroll
    for (int q = 0; q < 12; q++) acc[f][q] = zero;

  int rr = lane & 15, ks = lane >> 4;
  const short* Ap[2];
#pragma unroll
  for (int f = 0; f < 2; f++)
    Ap[f] = A + (size_t)(m0 + f * 16 + rr) * 512 + ks * 8;

  for (int kt = 0; kt < KT; ++kt){
    bf16x8 ahb[2];
#pragma unroll
    for (int f = 0; f < 2; f++)
      ahb[f] = as_bf(*(const short8*)(Ap[f] + kt * 32));
#pragma unroll
    for (int q = 0; q < 12; q++){
      int bo = (((nb + q) * KT + kt) * 64 + lane) * 8;
      bf16x8 bh = as_bf(*(const short8*)(Bhi + bo));
#pragma unroll
      for (int f = 0; f < 2; f++)
        acc[f][q] = MFMA_BF16(ahb[f], bh, acc[f][q], 0, 0, 0);
    }
  }
  int nc = lane & 15;
  int rb = lane >> 4;
#pragma unroll
  for (int q = 0; q < 12; q++){
    int n = (nb + q) * 16 + nc;
    float bias = b1[n] + (n < 512 ? b2[n] : 0.0f);
#pragma unroll
    for (int f = 0; f < 2; f++)
#pragma unroll
      for (int i = 0; i < 4; i++)
        C[(size_t)(m0 + f * 16 + rb * 4 + i) * G3 + n] = acc[f][q][i] + bias;
  }
}

// ---------- fused leaf GRU: 16 rows/WG, W_hh kt0..4 register-resident ----------
// grid = 256 WGs = 1 block/CU -> launch_bounds(512,1): full 256-VGPR budget,
// whr[5][6] (120 VGPRs) can actually stay resident (R8 failed due to 128-cap).
// Output written as bf16-hi shorts (feeds gemm1p).
template<int D, int KI>
__device__ __forceinline__ void leaf_body(
    const float* __restrict__ x, const short* __restrict__ Wih,
    const short* __restrict__ Whh, const float* __restrict__ bih,
    const float* __restrict__ bhh, short* __restrict__ outp, int ooff,
    float* __restrict__ hs, int b0, int t0, int tcnt,
    short* hhi, short* hlo, short* xhi)
{
  constexpr int XP  = D + 8;
  constexpr int NST = 2 * D;
  constexpr int CPR = D / 8;
  int tid = threadIdx.x, w = tid >> 6, lane = tid & 63;
  int arow = lane & 15, kgrp = lane >> 4;
  int c0 = w * 16 + arow;
  int msk = (arow & 7) << 4;

  float bir[2], biz[2], bin_[2], bhn[2];
#pragma unroll
  for (int j = 0; j < 2; j++){
    int c = c0 + j * 128;
    bir[j] = bih[c] + bhh[c];
    biz[j] = bih[256 + c] + bhh[256 + c];
    bin_[j] = bih[512 + c];
    bhn[j] = bhh[512 + c];
  }

  int srow = tid / CPR, scol = (tid % CPR) * 8;
  bool stg = tid < NST;
  const float* sx = x + ((size_t)(b0 + srow) * T_SZ + t0) * D + scol;
  short* xwh = xhi + srow * XP + scol;

  float hreg[2][4];
#pragma unroll
  for (int j = 0; j < 2; j++)
#pragma unroll
  for (int i = 0; i < 4; i++){
    int row = kgrp * 4 + i, c = c0 + j * 128;
    float v = hs[(size_t)(b0 + row) * H_SZ + c];
    hreg[j][i] = v;
    short h_, l_; cvt_hilo(v, h_, l_);
    int off = row * 512 + ((c * 2) ^ ((row & 7) << 4));
    *(short*)((char*)hhi + off) = h_;
    *(short*)((char*)hlo + off) = l_;
  }
  if (stg){
    f32x4 a0 = *(const f32x4*)sx;
    f32x4 a1 = *(const f32x4*)(sx + 4);
    short8 h8;
#pragma unroll
    for (int i = 0; i < 4; i++){ h8[i] = (short)f2bf(a0[i]); h8[4+i] = (short)f2bf(a1[i]); }
    *(short8*)xwh = h8;
  }
  __syncthreads();

  // W_hh kt 0..4 resident (120 VGPRs — now under the 256 budget)
  short8 whr[5][6];
#pragma unroll
  for (int kt = 0; kt < 5; kt++)
#pragma unroll
    for (int q = 0; q < 6; q++)
      whr[kt][q] = *(const short8*)(Whh + (((w + 8 * q) * 8 + kt) * 64 + lane) * 8);

  const char* hhp = (const char*)hhi + arow * 512;
  const char* hlp = (const char*)hlo + arow * 512;
  const char* xhp = (const char*)xhi + (arow * XP + kgrp * 8) * 2;

  const f32x4 zero = {0.f, 0.f, 0.f, 0.f};
  for (int t = 0; t < tcnt; t++){
    f32x4 acc[6], accNi[2];
#pragma unroll
    for (int q = 0; q < 6; q++) acc[q] = zero;
    accNi[0] = zero; accNi[1] = zero;

    short8 wb[6], wn[6];
    // ---- ih phase: x-hi from LDS, W_ih streamed with 1-ahead ring ----
#pragma unroll
    for (int q = 0; q < 6; q++)
      wb[q] = *(const short8*)(Wih + (((w + 8 * q) * KI) * 64 + lane) * 8);
#pragma unroll
    for (int kt = 0; kt < KI; kt++){
      if (kt + 1 < KI){
#pragma unroll
        for (int q = 0; q < 6; q++)
          wn[q] = *(const short8*)(Wih + (((w + 8 * q) * KI + kt + 1) * 64 + lane) * 8);
      }
      bf16x8 ah = as_bf(*(const short8*)(xhp + kt * 64));
#pragma unroll
      for (int q = 0; q < 6; q++){
        bf16x8 bw = as_bf(wb[q]);
        if (q < 4) acc[q] = MFMA_BF16(ah, bw, acc[q], 0, 0, 0);
        else       accNi[q-4] = MFMA_BF16(ah, bw, accNi[q-4], 0, 0, 0);
      }
      if (kt + 1 < KI){
#pragma unroll
        for (int q = 0; q < 6; q++) wb[q] = wn[q];
      }
    }
    // ---- hh phase: kt0..4 from registers (kt5 preloaded for stream) ----
#pragma unroll
    for (int q = 0; q < 6; q++)
      wb[q] = *(const short8*)(Whh + (((w + 8 * q) * 8 + 5) * 64 + lane) * 8);
#pragma unroll
    for (int kt = 0; kt < 5; kt++){
      int kb = (kt * 64 + kgrp * 16) ^ msk;
      bf16x8 ah = as_bf(*(const short8*)(hhp + kb));
      bf16x8 al = as_bf(*(const short8*)(hlp + kb));
#pragma unroll
      for (int q = 0; q < 6; q++){
        bf16x8 bw = as_bf(whr[kt][q]);
        acc[q] = MFMA_BF16(ah, bw, acc[q], 0, 0, 0);
        acc[q] = MFMA_BF16(al, bw, acc[q], 0, 0, 0);
      }
    }
#pragma unroll
    for (int kt = 5; kt < 8; kt++){
      if (kt < 7){
#pragma unroll
        for (int q = 0; q < 6; q++)
          wn[q] = *(const short8*)(Whh + (((w + 8 * q) * 8 + kt + 1) * 64 + lane) * 8);
      }
      int kb = (kt * 64 + kgrp * 16) ^ msk;
      bf16x8 ah = as_bf(*(const short8*)(hhp + kb));
      bf16x8 al = as_bf(*(const short8*)(hlp + kb));
#pragma unroll
      for (int q = 0; q < 6; q++){
        bf16x8 bw = as_bf(wb[q]);
        acc[q] = MFMA_BF16(ah, bw, acc[q], 0, 0, 0);
        acc[q] = MFMA_BF16(al, bw, acc[q], 0, 0, 0);
      }
      if (kt < 7){
#pragma unroll
        for (int q = 0; q < 6; q++) wb[q] = wn[q];
      }
    }
    __syncthreads();   // b1

    f32x4 a0, a1;
    bool ds = stg && (t + 1 < tcnt);
    if (ds){
      a0 = *(const f32x4*)(sx + (size_t)(t + 1) * D);
      a1 = *(const f32x4*)(sx + (size_t)(t + 1) * D + 4);
    }

#pragma unroll
    for (int j = 0; j < 2; j++)
#pragma unroll
    for (int i = 0; i < 4; i++){
      float rr = sigm(acc[j][i] + bir[j]);
      float zz = sigm(acc[2 + j][i] + biz[j]);
      float nn = tanh_(accNi[j][i] + bin_[j] + rr * (acc[4 + j][i] + bhn[j]));
      float hv = (1.0f - zz) * nn + zz * hreg[j][i];
      hreg[j][i] = hv;
      int row = kgrp * 4 + i, c = c0 + j * 128;
      short h_, l_; cvt_hilo(hv, h_, l_);
      outp[((size_t)(b0 + row) * tcnt + t) * 512 + ooff + c] = h_;   // bf16-hi out
      int off = row * 512 + ((c * 2) ^ ((row & 7) << 4));
      *(short*)((char*)hhi + off) = h_;
      *(short*)((char*)hlo + off) = l_;
    }
    if (ds){
      short8 h8;
#pragma unroll
      for (int i = 0; i < 4; i++){ h8[i] = (short)f2bf(a0[i]); h8[4+i] = (short)f2bf(a1[i]); }
      *(short8*)xwh = h8;
    }
    __syncthreads();   // b2
  }

#pragma unroll
  for (int j = 0; j < 2; j++)
#pragma unroll
  for (int i = 0; i < 4; i++){
    int row = kgrp * 4 + i;
    hs[(size_t)(b0 + row) * H_SZ + c0 + j * 128] = hreg[j][i];
  }
}

__global__ __launch_bounds__(512, 1) void gru_leaf(
    const float* __restrict__ x0, const short* __restrict__ Wih0,
    const short* __restrict__ Whh0, const float* __restrict__ bih0,
    const float* __restrict__ bhh0, short* __restrict__ out0, int ooff0,
    float* __restrict__ hs0,
    const float* __restrict__ x1, const short* __restrict__ Wih1,
    const short* __restrict__ Whh1, const float* __restrict__ bih1,
    const float* __restrict__ bhh1, short* __restrict__ out1, int ooff1,
    float* __restrict__ hs1,
    int nwg0, int t0, int tcnt)
{
  __shared__ short hhi[16 * 256];
  __shared__ short hlo[16 * 256];
  __shared__ short xhi[16 * 136];
  if ((int)blockIdx.x < nwg0)
    leaf_body<128, 4>(x0, Wih0, Whh0, bih0, bhh0, out0, ooff0, hs0,
                      blockIdx.x * 16, t0, tcnt, hhi, hlo, xhi);
  else
    leaf_body<96, 3>(x1, Wih1, Whh1, bih1, bhh1, out1, ooff1, hs1,
                     (blockIdx.x - nwg0) * 16, t0, tcnt, hhi, hlo, xhi);
}

// ---------- inter GRU + fused attention ----------
// Wave 0 computes scores for out-row t-1 (from hhi LDS state) during the MFMA
// phase of step t; esh crosses barrier b1; all threads accumulate ctx before
// overwriting hreg. Epilogue covers the chunk's last row.
__global__ __launch_bounds__(512, 1) void gru_inter(
    const float* __restrict__ gi,       // [B*tcnt, 768] chunk-local fp32
    const short* __restrict__ Whh, const float* __restrict__ bhh,
    const short* __restrict__ WvT,      // 3 q x 8 kt x 64 x 8 bf16
    const float* __restrict__ bv, const float* __restrict__ wu,
    float* __restrict__ ctx, float* __restrict__ lsum,
    float* __restrict__ hs, int tcnt)
{
  __shared__ short hhi[16 * 256];
  __shared__ short hlo[16 * 256];
  __shared__ short wvl[3 * 8 * 64 * 8];   // 24 KB
  __shared__ float esh[16];
  int b0 = blockIdx.x * 16;
  int tid = threadIdx.x, w = tid >> 6, lane = tid & 63;
  int arow = lane & 15, kgrp = lane >> 4;
  int c0 = w * 16 + arow;
  int msk = (arow & 7) << 4;

  float bhn[2];
  bhn[0] = bhh[512 + c0];
  bhn[1] = bhh[512 + c0 + 128];

  // attention constants (used by wave 0; a = q*16 + arow)
  float wuv[3], bvv[3];
#pragma unroll
  for (int q = 0; q < 3; q++){
    int a = q * 16 + arow;
    wuv[q] = (a < A_SZ) ? wu[a] : 0.0f;
    bvv[q] = (a < A_SZ) ? bv[a] : 0.0f;
  }

  // stage WvT bricks into LDS
  for (int i = tid; i < 3 * 8 * 64; i += 512)
    *(short8*)(wvl + i * 8) = *(const short8*)(WvT + (size_t)i * 8);

  float hreg[2][4];
#pragma unroll
  for (int j = 0; j < 2; j++)
#pragma unroll
  for (int i = 0; i < 4; i++){
    int row = kgrp * 4 + i, c = c0 + j * 128;
    float v = hs[(size_t)(b0 + row) * H_SZ + c];
    hreg[j][i] = v;
    short h_, l_; cvt_hilo(v, h_, l_);
    int off = row * 512 + ((c * 2) ^ ((row & 7) << 4));
    *(short*)((char*)hhi + off) = h_;
    *(short*)((char*)hlo + off) = l_;
  }
  __syncthreads();

  const char* hhp = (const char*)hhi + arow * 512;
  const char* hlp = (const char*)hlo + arow * 512;
  const float* gp[4];
#pragma unroll
  for (int i = 0; i < 4; i++)
    gp[i] = gi + (size_t)(b0 + kgrp * 4 + i) * tcnt * G3;

  float ctxa[2][4] = {{0.f,0.f,0.f,0.f},{0.f,0.f,0.f,0.f}};
  float lsr[4] = {0.f, 0.f, 0.f, 0.f};

  const f32x4 zero = {0.f, 0.f, 0.f, 0.f};
  for (int t = 0; t < tcnt; t++){
    float gvr[2][4], gvz[2][4], gvn[2][4];
#pragma unroll
    for (int j = 0; j < 2; j++)
#pragma unroll
    for (int i = 0; i < 4; i++){
      const float* g = gp[i] + (size_t)t * G3 + c0 + j * 128;
      gvr[j][i] = g[0];
      gvz[j][i] = g[256];
      gvn[j][i] = g[512];
    }

    f32x4 acc[6];
#pragma unroll
    for (int q = 0; q < 6; q++) acc[q] = zero;

    short8 wb[6], wn[6];
#pragma unroll
    for (int q = 0; q < 6; q++)
      wb[q] = *(const short8*)(Whh + (((w + 8 * q) * 8) * 64 + lane) * 8);
#pragma unroll
    for (int kt = 0; kt < 8; kt++){
      if (kt < 7){
#pragma unroll
        for (int q = 0; q < 6; q++)
          wn[q] = *(const short8*)(Whh + (((w + 8 * q) * 8 + kt + 1) * 64 + lane) * 8);
      }
      int kb = (kt * 64 + kgrp * 16) ^ msk;
      bf16x8 ah = as_bf(*(const short8*)(hhp + kb));
      bf16x8 al = as_bf(*(const short8*)(hlp + kb));
#pragma unroll
      for (int q = 0; q < 6; q++){
        bf16x8 bw = as_bf(wb[q]);
        acc[q] = MFMA_BF16(ah, bw, acc[q], 0, 0, 0);
        acc[q] = MFMA_BF16(al, bw, acc[q], 0, 0, 0);
      }
      if (kt < 7){
#pragma unroll
        for (int q = 0; q < 6; q++) wb[q] = wn[q];
      }
    }

    // ---- wave 0: scores for out-row t-1 (state currently in hhi) ----
    if (w == 0 && t > 0){
      f32x4 um[3];
#pragma unroll
      for (int q = 0; q < 3; q++) um[q] = zero;
#pragma unroll
      for (int kt = 0; kt < 8; kt++){
        int kb = (kt * 64 + kgrp * 16) ^ msk;
        bf16x8 ah = as_bf(*(const short8*)(hhp + kb));
#pragma unroll
        for (int q = 0; q < 3; q++){
          bf16x8 bw = as_bf(*(const short8*)(wvl + ((q * 8 + kt) * 64 + lane) * 8));
          um[q] = MFMA_BF16(ah, bw, um[q], 0, 0, 0);
        }
      }
      f32x4 sp;
#pragma unroll
      for (int i = 0; i < 4; i++){
        float v = 0.f;
#pragma unroll
        for (int q = 0; q < 3; q++)
          v += wuv[q] * tanh_(um[q][i] + bvv[q]);
        sp[i] = v;
      }
#pragma unroll
      for (int d = 1; d < 16; d <<= 1){
#pragma unroll
        for (int i = 0; i < 4; i++)
          sp[i] += __shfl_xor(sp[i], d);
      }
      if (arow == 0){
#pragma unroll
        for (int i = 0; i < 4; i++){
          float e = __expf(sp[i]);
          esh[kgrp * 4 + i] = e;
          lsr[i] += e;
        }
      }
    }
    __syncthreads();   // b1 (also publishes esh)

    // ---- ctx accumulation for out-row t-1 (hreg still holds it) ----
    if (t > 0){
#pragma unroll
      for (int i = 0; i < 4; i++){
        float e = esh[kgrp * 4 + i];
#pragma unroll
        for (int j = 0; j < 2; j++)
          ctxa[j][i] += e * hreg[j][i];
      }
    }

#pragma unroll
    for (int j = 0; j < 2; j++)
#pragma unroll
    for (int i = 0; i < 4; i++){
      float rr = sigm(gvr[j][i] + acc[j][i]);
      float zz = sigm(gvz[j][i] + acc[2 + j][i]);
      float nn = tanh_(gvn[j][i] + rr * (acc[4 + j][i] + bhn[j]));
      float hv = (1.0f - zz) * nn + zz * hreg[j][i];
      hreg[j][i] = hv;
      int row = kgrp * 4 + i, c = c0 + j * 128;
      short h_, l_; cvt_hilo(hv, h_, l_);
      int off = row * 512 + ((c * 2) ^ ((row & 7) << 4));
      *(short*)((char*)hhi + off) = h_;
      *(short*)((char*)hlo + off) = l_;
    }
    __syncthreads();   // b2
  }

  // ---- epilogue: scores + ctx for the last row (tcnt-1) ----
  if (w == 0){
    f32x4 um[3];
#pragma unroll
    for (int q = 0; q < 3; q++) um[q] = zero;
#pragma unroll
    for (int kt = 0; kt < 8; kt++){
      int kb = (kt * 64 + kgrp * 16) ^ msk;
      bf16x8 ah = as_bf(*(const short8*)(hhp + kb));
#pragma unroll
      for (int q = 0; q < 3; q++){
        bf16x8 bw = as_bf(*(const short8*)(wvl + ((q * 8 + kt) * 64 + lane) * 8));
        um[q] = MFMA_BF16(ah, bw, um[q], 0, 0, 0);
      }
    }
    f32x4 sp;
#pragma unroll
    for (int i = 0; i < 4; i++){
      float v = 0.f;
#pragma unroll
      for (int q = 0; q < 3; q++)
        v += wuv[q] * tanh_(um[q][i] + bvv[q]);
      sp[i] = v;
    }
#pragma unroll
    for (int d = 1; d < 16; d <<= 1){
#pragma unroll
      for (int i = 0; i < 4; i++)
        sp[i] += __shfl_xor(sp[i], d);
    }
    if (arow == 0){
#pragma unroll
      for (int i = 0; i < 4; i++){
        float e = __expf(sp[i]);
        esh[kgrp * 4 + i] = e;
        lsr[i] += e;
      }
    }
  }
  __syncthreads();
#pragma unroll
  for (int i = 0; i < 4; i++){
    float e = esh[kgrp * 4 + i];
#pragma unroll
    for (int j = 0; j < 2; j++)
      ctxa[j][i] += e * hreg[j][i];
  }

  // persist h state, ctx partials, lsum
#pragma unroll
  for (int j = 0; j < 2; j++)
#pragma unroll
  for (int i = 0; i < 4; i++){
    int row = kgrp * 4 + i;
    hs[(size_t)(b0 + row) * H_SZ + c0 + j * 128] = hreg[j][i];
    ctx[(size_t)(b0 + row) * H_SZ + c0 + j * 128] += ctxa[j][i];
  }
  if (w == 0 && arow == 0){
#pragma unroll
    for (int i = 0; i < 4; i++)
      lsum[b0 + kgrp * 4 + i] += lsr[i];
  }
}

__global__ __launch_bounds__(256, 1) void attn_fin(
    const float* __restrict__ ctx, const float* __restrict__ lsum,
    float* __restrict__ out)
{
  int b = blockIdx.x, tid = threadIdx.x;
  out[(size_t)b * H_SZ + tid] = ctx[(size_t)b * H_SZ + tid] / lsum[b];
}

// ---------- host ----------
extern "C" void kernel_launch(void* const* d_in, const int* in_sizes, int n_in,
                              void* d_out, int out_size, void* d_ws, size_t ws_size,
                              hipStream_t stream)
{
  (void)in_sizes; (void)n_in; (void)out_size;
  const float* crime = (const float*)d_in[0];
  const float* anom  = (const float*)d_in[1];
  const float* WihC = (const float*)d_in[2];
  const float* WhhC = (const float*)d_in[3];
  const float* bihC = (const float*)d_in[4];
  const float* bhhC = (const float*)d_in[5];
  const float* WihA = (const float*)d_in[6];
  const float* WhhA = (const float*)d_in[7];
  const float* bihA = (const float*)d_in[8];
  const float* bhhA = (const float*)d_in[9];
  const float* WihI = (const float*)d_in[10];
  const float* WhhI = (const float*)d_in[11];
  const float* bihI = (const float*)d_in[12];
  const float* bhhI = (const float*)d_in[13];
  const float* Wv = (const float*)d_in[14];
  const float* bv = (const float*)d_in[15];
  const float* wu = (const float*)d_in[16];
  float* out = (float*)d_out;

  char* ws = (char*)d_ws;
  size_t off = 0;
  auto take = [&](size_t n){ size_t r = off; off += (n + 255) & ~(size_t)255; return r; };

  short* pIhC = (short*)(ws + take((size_t)G3 * 128 * 2));
  short* pHhC = (short*)(ws + take((size_t)G3 * 256 * 2));
  short* pIhA = (short*)(ws + take((size_t)G3 * 96 * 2));
  short* pHhA = (short*)(ws + take((size_t)G3 * 256 * 2));
  short* pIhI = (short*)(ws + take((size_t)G3 * 512 * 2));
  short* pHhI = (short*)(ws + take((size_t)G3 * 256 * 2));
  short* pWvT = (short*)(ws + take((size_t)3 * 8 * 64 * 8 * 2));

  size_t state_off = off;
  float* hsC  = (float*)(ws + take((size_t)B_SZ * H_SZ * 4));
  float* hsA  = (float*)(ws + take((size_t)B_SZ * H_SZ * 4));
  float* hsI  = (float*)(ws + take((size_t)B_SZ * H_SZ * 4));
  float* ctx  = (float*)(ws + take((size_t)B_SZ * H_SZ * 4));
  float* lsum = (float*)(ws + take((size_t)B_SZ * 4));
  size_t state_end = off;

  // adaptive T-chunk: Gi fp32 (768) + OcaH bf16 (512 shorts) per timestep
  size_t per = (size_t)B_SZ * (G3 * 4 + 512 * 2);   // 8.39 MB per timestep
  size_t avail = (ws_size > off + 4096) ? (ws_size - off - 4096) : 0;
  int TC = (int)(avail / per);
  if (TC < 1) TC = 1;
  if (TC > T_SZ) TC = T_SZ;

  float* Gi   = (float*)(ws + take((size_t)B_SZ * TC * G3 * 4));
  short* OcaH = (short*)(ws + take((size_t)B_SZ * TC * 512 * 2));

  // zero h-states, ctx, lsum (every launch: deterministic)
  zinit<<<2048, 256, 0, stream>>>((float*)(ws + state_off), (state_end - state_off) / 4);

  // pack all weight bricks + WvT in one dispatch
  packall<<<2280, 64, 0, stream>>>(WihC, WhhC, WihA, WhhA, WihI, WhhI, Wv,
                                   pIhC, pHhC, pIhA, pHhA, pIhI, pHhI, pWvT);

  for (int t0 = 0; t0 < T_SZ; ){
    int tcnt = T_SZ - t0 < TC ? T_SZ - t0 : TC;
    int rows = B_SZ * tcnt;
    // fused leaf GRUs: crime -> OcaH[:,0:256], anomaly -> OcaH[:,256:512]
    gru_leaf<<<256, 512, 0, stream>>>(
        crime, pIhC, pHhC, bihC, bhhC, OcaH, 0,   hsC,
        anom,  pIhA, pHhA, bihA, bhhA, OcaH, 256, hsA,
        128, t0, tcnt);
    // inter projection (1-pass bf16 A) + recurrence with fused attention
    gemm1p<<<rows / 64, 512, 0, stream>>>(OcaH, pIhI, bihI, bhhI, Gi);
    gru_inter<<<128, 512, 0, stream>>>(Gi, pHhI, bhhI, pWvT, bv, wu,
                                       ctx, lsum, hsI, tcnt);
    t0 += tcnt;
  }
  attn_fin<<<B_SZ, 256, 0, stream>>>(ctx, lsum, out);
}